// Round 7
// baseline (316.889 us; speedup 1.0000x reference)
//
#include <hip/hip_runtime.h>

// ---------------------------------------------------------------------------
// Compile-time Cayley table for Cl(4,0), blades in short-lex order.
// For each (i,k): exactly one output blade j = idx(ba ^ bb), sign from
// merge-swap parity (metric all +1). constexpr => folded after unrolling.
// ---------------------------------------------------------------------------
struct Tables {
    signed char  sgn[16][16];
    unsigned char out[16][16];
};

constexpr int pc4(int x) {
    return ((x >> 0) & 1) + ((x >> 1) & 1) + ((x >> 2) & 1) + ((x >> 3) & 1);
}

constexpr Tables make_tables() {
    Tables t{};
    int bitmaps[16] = {};
    int n = 0;
    for (int g = 0; g <= 4; ++g)
        for (int bm = 0; bm < 16; ++bm)
            if (pc4(bm) == g) bitmaps[n++] = bm;
    int inv[16] = {};
    for (int i = 0; i < 16; ++i) inv[bitmaps[i]] = i;
    for (int i = 0; i < 16; ++i) {
        for (int k = 0; k < 16; ++k) {
            const int ba = bitmaps[i];
            const int bb = bitmaps[k];
            int swaps = 0;
            for (int sh = ba >> 1; sh; sh >>= 1) swaps += pc4(sh & bb);
            t.sgn[i][k] = (swaps & 1) ? -1 : 1;
            t.out[i][k] = (unsigned char)inv[ba ^ bb];
        }
    }
    return t;
}

constexpr Tables TBL = make_tables();

// Native clang vector type: accepted by __builtin_nontemporal_store
// (HIP_vector_type float4 is a class and is rejected). Same 16B layout.
typedef float f32x4 __attribute__((ext_vector_type(4)));

// ROW = 20 floats (80 B): 16B-aligned rows => all LDS ops are b128;
// start bank 20*t mod 32 spreads over 8 banksets => <=4-way conflicts (1.58x).
// LDS/block = 2*256*20*4 = 40960 B.
#define ROW 20

__global__ __launch_bounds__(256) void clifford_gp_kernel(
        const float4* __restrict__ a4,
        const float4* __restrict__ b4,
        float4* __restrict__ o4,
        int n_mv) {
    __shared__ __align__(16) float lds_a[256 * ROW];
    __shared__ __align__(16) float lds_b[256 * ROW];

    const int t = threadIdx.x;
    const long long base4 = (long long)blockIdx.x * 1024;  // tile base (float4 units)
    const long long n4 = (long long)n_mv * 4;
    const bool full = (base4 + 1024) <= n4;   // uniform: whole tile in range

    // ---- phase 1: issue ALL 8 global loads before ANY LDS write (MLP = 8).
    //      Plain (caching) loads: inputs are L3-hot from the harness restore.
    float4 va[4], vb[4];
    if (full) {
        #pragma unroll
        for (int r = 0; r < 4; ++r) va[r] = a4[base4 + r * 256 + t];
        #pragma unroll
        for (int r = 0; r < 4; ++r) vb[r] = b4[base4 + r * 256 + t];
    } else {
        #pragma unroll
        for (int r = 0; r < 4; ++r) {
            const long long g = base4 + r * 256 + t;
            va[r] = (g < n4) ? a4[g] : make_float4(0.f, 0.f, 0.f, 0.f);
            vb[r] = (g < n4) ? b4[g] : make_float4(0.f, 0.f, 0.f, 0.f);
        }
    }

    // ---- phase 2: scatter into padded LDS rows (b128 stores, 16B-aligned)
    #pragma unroll
    for (int r = 0; r < 4; ++r) {
        const int idx = r * 256 + t;
        const int mv = idx >> 2;
        const int q  = idx & 3;
        *reinterpret_cast<float4*>(&lds_a[mv * ROW + q * 4]) = va[r];
        *reinterpret_cast<float4*>(&lds_b[mv * ROW + q * 4]) = vb[r];
    }
    __syncthreads();

    // ---- phase 3: own row -> registers (b128 reads), 256 signed FMAs
    float av[16], bv[16], ov[16];
    #pragma unroll
    for (int j = 0; j < 4; ++j) {
        const float4 ta = *reinterpret_cast<const float4*>(&lds_a[t * ROW + j * 4]);
        av[j * 4 + 0] = ta.x; av[j * 4 + 1] = ta.y;
        av[j * 4 + 2] = ta.z; av[j * 4 + 3] = ta.w;
        const float4 tb = *reinterpret_cast<const float4*>(&lds_b[t * ROW + j * 4]);
        bv[j * 4 + 0] = tb.x; bv[j * 4 + 1] = tb.y;
        bv[j * 4 + 2] = tb.z; bv[j * 4 + 3] = tb.w;
    }

    #pragma unroll
    for (int j = 0; j < 16; ++j) ov[j] = 0.0f;

    #pragma unroll
    for (int i = 0; i < 16; ++i) {
        #pragma unroll
        for (int k = 0; k < 16; ++k) {
            const int j = TBL.out[i][k];       // compile-time constant
            if (TBL.sgn[i][k] > 0) {
                ov[j] = fmaf(av[i], bv[k], ov[j]);
            } else {
                ov[j] = fmaf(-av[i], bv[k], ov[j]);
            }
        }
    }

    // ---- phase 4: result row back to LDS (row-private; barrier; gather-out)
    #pragma unroll
    for (int j = 0; j < 4; ++j) {
        *reinterpret_cast<float4*>(&lds_a[t * ROW + j * 4]) =
            make_float4(ov[j * 4 + 0], ov[j * 4 + 1], ov[j * 4 + 2], ov[j * 4 + 3]);
    }
    __syncthreads();

    // ---- output: NON-TEMPORAL stores (global_store_dwordx4 ... nt).
    //      No L3 allocation => output stream stops evicting the L3-hot
    //      inputs => FETCH_SIZE collapses; HBM bytes ~256MB -> ~140MB.
    f32x4* onv = reinterpret_cast<f32x4*>(o4);
    if (full) {
        #pragma unroll
        for (int r = 0; r < 4; ++r) {
            const int idx = r * 256 + t;
            const int mv = idx >> 2;
            const int q  = idx & 3;
            const f32x4 v =
                *reinterpret_cast<const f32x4*>(&lds_a[mv * ROW + q * 4]);
            __builtin_nontemporal_store(v, &onv[base4 + idx]);
        }
    } else {
        #pragma unroll
        for (int r = 0; r < 4; ++r) {
            const int idx = r * 256 + t;
            if (base4 + idx < n4) {
                const int mv = idx >> 2;
                const int q  = idx & 3;
                const f32x4 v =
                    *reinterpret_cast<const f32x4*>(&lds_a[mv * ROW + q * 4]);
                __builtin_nontemporal_store(v, &onv[base4 + idx]);
            }
        }
    }
}

extern "C" void kernel_launch(void* const* d_in, const int* in_sizes, int n_in,
                              void* d_out, int out_size, void* d_ws, size_t ws_size,
                              hipStream_t stream) {
    const float4* a4 = (const float4*)d_in[0];
    const float4* b4 = (const float4*)d_in[1];
    // d_in[2] (cayley) intentionally unused: table folded at compile time.
    float4* o4 = (float4*)d_out;

    const int n_mv = in_sizes[0] / 16;            // 2048*1024 = 2,097,152
    const int block = 256;
    const int grid = (n_mv + block - 1) / block;  // 8192 blocks

    clifford_gp_kernel<<<grid, block, 0, stream>>>(a4, b4, o4, n_mv);
}